// Round 10
// baseline (1100.755 us; speedup 1.0000x reference)
//
#include <hip/hip_runtime.h>
#include <hip/hip_cooperative_groups.h>
#include <hip/hip_bf16.h>
#include <math.h>

namespace cg = cooperative_groups;

// N=50000, E=500000, SED=128, HID=64, H=2, F_node=128
// Round 10: single cooperative mega-kernel; 11 phases separated by grid.sync.
// Phase bodies = Round 9 kernels (verified) as grid-stride task loops.

typedef short short8 __attribute__((ext_vector_type(8)));
typedef float floatx4 __attribute__((ext_vector_type(4)));
typedef float v2f __attribute__((ext_vector_type(2)));
typedef unsigned uint2v __attribute__((ext_vector_type(2)));

__device__ __forceinline__ v2f bfpair(unsigned v) {
    uint2v t; t.x = v << 16; t.y = v & 0xFFFF0000u;
    return __builtin_bit_cast(v2f, t);
}
__device__ __forceinline__ unsigned short bfbits(float f) {
    return __builtin_bit_cast(unsigned short, __float2bfloat16(f));
}
__device__ __forceinline__ unsigned packbf(float a, float b) {
    return ((unsigned)bfbits(b) << 16) | (unsigned)bfbits(a);
}
__device__ __forceinline__ float lrelu(float v) { return v > 0.f ? v : 0.2f * v; }

struct MegaParams {
    const float* x; const int* src; const int* dst;
    const float* cls; const float* fc0_w; const float* fc0_b;
    const float* W1; const float* att_s1; const float* att_d1; const float* bias1;
    const float* W2; const float* att_s2; const float* att_d2; const float* bias2;
    const float* fc2_w; const float* fc2_b; const float* fc3_w; const float* fc3_b;
    float* out;
    float* c1; __hip_bfloat16* w1frag; __hip_bfloat16* w2frag; __hip_bfloat16* fc2frag;
    float* a_s1; float* a_d1; float* a_s2; float* a_d2;
    __hip_bfloat16* h1bf; __hip_bfloat16* hmid; __hip_bfloat16* h2pre;
    __hip_bfloat16* h2bf; __hip_bfloat16* zsd;
    int* counts; int* rowp; int* woff; int* srcs; int* bsum; int* boff;
    int N, E, nb;
};

__global__ void __launch_bounds__(256, 4) mega_kernel(MegaParams p) {
    cg::grid_group grid = cg::this_grid();
    const int tid = threadIdx.x;
    const int G = gridDim.x;
    const int lane = tid & 63, wv = tid >> 6;
    const int lo = lane & 15, quad = lane >> 4;
    const int N = p.N, E = p.E;

    __shared__ float s_sent[128];
    __shared__ int s_wsum[16];

    // ================= P0: zero counts, c1, frag tables =================
    for (int i = blockIdx.x * 256 + tid; i < N; i += G * 256) p.counts[i] = 0;
    if (blockIdx.x == 0) {
        if (tid < 128) {
            float acc = p.fc0_b[tid];
            const float* row = p.fc0_w + (size_t)tid * 768;
            for (int k = 0; k < 768; ++k) acc += row[k] * p.cls[k];
            s_sent[tid] = acc;
        }
        __syncthreads();
        if (tid < 128) {
            float acc = 0.f;
            for (int k = 0; k < 128; ++k) acc += s_sent[k] * p.W1[(128 + k) * 128 + tid];
            p.c1[tid] = acc;
        }
    }
    {
        int g = blockIdx.x * 256 + tid, gs = G * 256;
        for (int i = g; i < 16384; i += gs) {
            int j = i & 7, l = (i >> 3) & 63, nt = (i >> 9) & 7, kt = (i >> 12) & 3;
            int k = kt * 32 + (l >> 4) * 8 + j;
            int n = nt * 16 + (l & 15);
            p.w1frag[i] = __float2bfloat16(p.W1[k * 128 + n]);
        }
        for (int i = g; i < 32768; i += gs) {
            int j = i & 7, l = (i >> 3) & 63, nt = (i >> 9) & 15, kt = (i >> 13) & 3;
            int k = kt * 32 + (l >> 4) * 8 + j;
            int n = nt * 16 + (l & 15);
            p.w2frag[i] = __float2bfloat16(p.W2[k * 256 + n]);
        }
        for (int i = g; i < 32768; i += gs) {
            int j = i & 7, l = (i >> 3) & 63, nt = (i >> 9) & 15, kt = (i >> 13) & 3;
            int k = kt * 32 + (l >> 4) * 8 + j;
            int n = nt * 16 + (l & 15);
            float v = (n < 128) ? p.fc2_w[n * 256 + k] : p.fc2_w[(n - 128) * 256 + 128 + k];
            p.fc2frag[i] = __float2bfloat16(v);
        }
    }
    grid.sync();

    // ================= P1: gemm1 (+logits) and degree count =================
    {
        int T = (N + 63) / 64;
        const short8* bf = (const short8*)p.w1frag;
        for (int tb = blockIdx.x; tb < T; tb += G) {
            int rowbase = (tb * 4 + wv) * 16;
            if (rowbase < N) {
                int arow = rowbase + lo; if (arow >= N) arow = N - 1;
                const float* ap = p.x + (size_t)arow * 128 + quad * 8;
                floatx4 acc[8];
                #pragma unroll
                for (int nt = 0; nt < 8; ++nt) acc[nt] = (floatx4){0.f, 0.f, 0.f, 0.f};
                #pragma unroll
                for (int kt = 0; kt < 4; ++kt) {
                    float4 fa = *(const float4*)(ap + kt * 32);
                    float4 fb = *(const float4*)(ap + kt * 32 + 4);
                    short8 a;
                    a[0] = (short)bfbits(fa.x); a[1] = (short)bfbits(fa.y);
                    a[2] = (short)bfbits(fa.z); a[3] = (short)bfbits(fa.w);
                    a[4] = (short)bfbits(fb.x); a[5] = (short)bfbits(fb.y);
                    a[6] = (short)bfbits(fb.z); a[7] = (short)bfbits(fb.w);
                    #pragma unroll
                    for (int nt = 0; nt < 8; ++nt)
                        acc[nt] = __builtin_amdgcn_mfma_f32_16x16x32_bf16(a, bf[(kt * 8 + nt) * 64 + lane], acc[nt], 0, 0, 0);
                }
                float ps0[4] = {0,0,0,0}, ps1[4] = {0,0,0,0}, pd0[4] = {0,0,0,0}, pd1[4] = {0,0,0,0};
                #pragma unroll
                for (int nt = 0; nt < 8; ++nt) {
                    int ch = nt * 16 + lo;
                    float cv = p.c1[ch], as_v = p.att_s1[ch], ad_v = p.att_d1[ch];
                    #pragma unroll
                    for (int r = 0; r < 4; ++r) {
                        int row = rowbase + quad * 4 + r;
                        float val = acc[nt][r] + cv;
                        if (row < N) ((unsigned short*)p.h1bf)[(size_t)row * 128 + ch] = bfbits(val);
                        if (nt < 4) { ps0[r] += val * as_v; pd0[r] += val * ad_v; }
                        else        { ps1[r] += val * as_v; pd1[r] += val * ad_v; }
                    }
                }
                #pragma unroll
                for (int r = 0; r < 4; ++r) {
                    int row = rowbase + quad * 4 + r;
                    float v0 = ps0[r], v1 = ps1[r], v2 = pd0[r], v3 = pd1[r];
                    #pragma unroll
                    for (int off = 1; off < 16; off <<= 1) {
                        v0 += __shfl_xor(v0, off, 64); v1 += __shfl_xor(v1, off, 64);
                        v2 += __shfl_xor(v2, off, 64); v3 += __shfl_xor(v3, off, 64);
                    }
                    if (lo == 0 && row < N) {
                        p.a_s1[row * 2 + 0] = v0; p.a_s1[row * 2 + 1] = v1;
                        p.a_d1[row * 2 + 0] = v2; p.a_d1[row * 2 + 1] = v3;
                    }
                }
            }
        }
        for (int e = blockIdx.x * 256 + tid; e < E; e += G * 256)
            atomicAdd(&p.counts[p.dst[e]], 1);
    }
    grid.sync();

    // ================= P2: per-chunk sums =================
    for (int tb = blockIdx.x; tb < p.nb; tb += G) {
        int base = tb * 1024;
        int v = 0;
        #pragma unroll
        for (int k = 0; k < 4; ++k) {
            int idx = base + k * 256 + tid;
            if (idx < N) v += p.counts[idx];
        }
        #pragma unroll
        for (int off = 1; off < 64; off <<= 1) v += __shfl_xor(v, off, 64);
        if (lane == 0) s_wsum[wv] = v;
        __syncthreads();
        if (tid == 0) p.bsum[tb] = s_wsum[0] + s_wsum[1] + s_wsum[2] + s_wsum[3];
        __syncthreads();
    }
    grid.sync();

    // ================= P3: top scan (1 wave) =================
    if (blockIdx.x == 0 && tid < 64) {
        int v = (tid < p.nb) ? p.bsum[tid] : 0;
        int x = v;
        #pragma unroll
        for (int off = 1; off < 64; off <<= 1) {
            int t = __shfl_up(x, off, 64);
            if (tid >= off) x += t;
        }
        if (tid < p.nb) p.boff[tid] = x - v;
    }
    grid.sync();

    // ================= P4: local scan (4 elems/thread) =================
    for (int tb = blockIdx.x; tb < p.nb; tb += G) {
        int i0 = tb * 1024 + tid * 4;
        int c[4]; int tsum = 0;
        #pragma unroll
        for (int k = 0; k < 4; ++k) {
            c[k] = (i0 + k < N) ? p.counts[i0 + k] : 0;
            tsum += c[k];
        }
        int x = tsum;
        #pragma unroll
        for (int off = 1; off < 64; off <<= 1) {
            int t = __shfl_up(x, off, 64);
            if (lane >= off) x += t;
        }
        if (lane == 63) s_wsum[wv] = x;
        __syncthreads();
        int add = 0;
        for (int w = 0; w < wv; ++w) add += s_wsum[w];
        int run = p.boff[tb] + add + x - tsum;
        #pragma unroll
        for (int k = 0; k < 4; ++k) {
            if (i0 + k < N) { p.rowp[i0 + k] = run; p.woff[i0 + k] = run; }
            run += c[k];
        }
        __syncthreads();
    }
    if (blockIdx.x == 0 && tid == 0) p.rowp[N] = E;
    grid.sync();

    // ================= P5: scatter =================
    for (int e = blockIdx.x * 256 + tid; e < E; e += G * 256) {
        int pos = atomicAdd(&p.woff[p.dst[e]], 1);
        p.srcs[pos] = p.src[e];
    }
    grid.sync();

    // ================= P6: agg1 (16 lanes/dst) =================
    {
        int T = (N + 15) / 16;
        const unsigned* h1u = (const unsigned*)p.h1bf;
        for (int tb = blockIdx.x; tb < T; tb += G) {
            int d = tb * 16 + (tid >> 4);
            if (d < N) {
                int q = tid & 15;
                int beg = p.rowp[d], end = p.rowp[d + 1];
                float2 adp = ((const float2*)p.a_d1)[d];
                float den0 = 0.f, den1 = 0.f;
                v2f facc2[4];
                #pragma unroll
                for (int m = 0; m < 4; ++m) facc2[m] = (v2f){0.f, 0.f};
                for (int i = beg; i < end; i += 2) {
                    int s0 = p.srcs[i];
                    bool has1 = (i + 1) < end;
                    int s1 = has1 ? p.srcs[i + 1] : s0;
                    float2 as0 = ((const float2*)p.a_s1)[s0];
                    float2 as1 = ((const float2*)p.a_s1)[s1];
                    uint4 u0 = ((const uint4*)(h1u + (size_t)s0 * 64))[q];
                    uint4 u1 = ((const uint4*)(h1u + (size_t)s1 * 64))[q];
                    float e00 = __expf(lrelu(as0.x + adp.x));
                    float e01 = __expf(lrelu(as0.y + adp.y));
                    float e10 = has1 ? __expf(lrelu(as1.x + adp.x)) : 0.f;
                    float e11 = has1 ? __expf(lrelu(as1.y + adp.y)) : 0.f;
                    den0 += e00 + e10;
                    den1 += e01 + e11;
                    float w0 = (q < 8) ? e00 : e01;
                    float w1 = (q < 8) ? e10 : e11;
                    facc2[0] += bfpair(u0.x) * w0 + bfpair(u1.x) * w1;
                    facc2[1] += bfpair(u0.y) * w0 + bfpair(u1.y) * w1;
                    facc2[2] += bfpair(u0.z) * w0 + bfpair(u1.z) * w1;
                    facc2[3] += bfpair(u0.w) * w0 + bfpair(u1.w) * w1;
                }
                float inv = 1.f / (((q < 8) ? den0 : den1) + 1e-16f);
                int c0 = 8 * q;
                float v[8];
                #pragma unroll
                for (int m = 0; m < 4; ++m) {
                    float va = facc2[m].x * inv + p.bias1[c0 + 2 * m];
                    float vb = facc2[m].y * inv + p.bias1[c0 + 2 * m + 1];
                    v[2 * m]     = va > 0.f ? va : expm1f(va);
                    v[2 * m + 1] = vb > 0.f ? vb : expm1f(vb);
                }
                uint4 o;
                o.x = packbf(v[0], v[1]); o.y = packbf(v[2], v[3]);
                o.z = packbf(v[4], v[5]); o.w = packbf(v[6], v[7]);
                ((uint4*)((unsigned*)p.hmid + (size_t)d * 64))[q] = o;
            }
        }
    }
    grid.sync();

    // ================= P7: gemm2 (+logits) =================
    {
        int T = (N + 63) / 64;
        const short8* bf = (const short8*)p.w2frag;
        for (int tb = blockIdx.x; tb < T; tb += G) {
            int rowbase = (tb * 4 + wv) * 16;
            if (rowbase < N) {
                int arow = rowbase + lo; if (arow >= N) arow = N - 1;
                const __hip_bfloat16* ap = p.hmid + (size_t)arow * 128 + quad * 8;
                floatx4 acc[16];
                #pragma unroll
                for (int nt = 0; nt < 16; ++nt) acc[nt] = (floatx4){0.f, 0.f, 0.f, 0.f};
                #pragma unroll
                for (int kt = 0; kt < 4; ++kt) {
                    short8 a = *(const short8*)(ap + kt * 32);
                    #pragma unroll
                    for (int nt = 0; nt < 16; ++nt)
                        acc[nt] = __builtin_amdgcn_mfma_f32_16x16x32_bf16(a, bf[(kt * 16 + nt) * 64 + lane], acc[nt], 0, 0, 0);
                }
                float ps0[4] = {0,0,0,0}, ps1[4] = {0,0,0,0}, pd0[4] = {0,0,0,0}, pd1[4] = {0,0,0,0};
                #pragma unroll
                for (int nt = 0; nt < 16; ++nt) {
                    int ch = nt * 16 + lo;
                    float as_v = p.att_s2[ch], ad_v = p.att_d2[ch];
                    #pragma unroll
                    for (int r = 0; r < 4; ++r) {
                        int row = rowbase + quad * 4 + r;
                        float val = acc[nt][r];
                        if (row < N) ((unsigned short*)p.h2pre)[(size_t)row * 256 + ch] = bfbits(val);
                        if (nt < 8) { ps0[r] += val * as_v; pd0[r] += val * ad_v; }
                        else        { ps1[r] += val * as_v; pd1[r] += val * ad_v; }
                    }
                }
                #pragma unroll
                for (int r = 0; r < 4; ++r) {
                    int row = rowbase + quad * 4 + r;
                    float v0 = ps0[r], v1 = ps1[r], v2 = pd0[r], v3 = pd1[r];
                    #pragma unroll
                    for (int off = 1; off < 16; off <<= 1) {
                        v0 += __shfl_xor(v0, off, 64); v1 += __shfl_xor(v1, off, 64);
                        v2 += __shfl_xor(v2, off, 64); v3 += __shfl_xor(v3, off, 64);
                    }
                    if (lo == 0 && row < N) {
                        p.a_s2[row * 2 + 0] = v0; p.a_s2[row * 2 + 1] = v1;
                        p.a_d2[row * 2 + 0] = v2; p.a_d2[row * 2 + 1] = v3;
                    }
                }
            }
        }
    }
    grid.sync();

    // ================= P8: agg2 (32 lanes/dst) =================
    {
        int T = (N + 7) / 8;
        const unsigned* h2u = (const unsigned*)p.h2pre;
        for (int tb = blockIdx.x; tb < T; tb += G) {
            int d = tb * 8 + (tid >> 5);
            if (d < N) {
                int q = tid & 31;
                int beg = p.rowp[d], end = p.rowp[d + 1];
                float2 adp = ((const float2*)p.a_d2)[d];
                float den0 = 0.f, den1 = 0.f;
                v2f facc2[4];
                #pragma unroll
                for (int m = 0; m < 4; ++m) facc2[m] = (v2f){0.f, 0.f};
                for (int i = beg; i < end; i += 2) {
                    int s0 = p.srcs[i];
                    bool has1 = (i + 1) < end;
                    int s1 = has1 ? p.srcs[i + 1] : s0;
                    float2 as0 = ((const float2*)p.a_s2)[s0];
                    float2 as1 = ((const float2*)p.a_s2)[s1];
                    uint4 u0 = ((const uint4*)(h2u + (size_t)s0 * 128))[q];
                    uint4 u1 = ((const uint4*)(h2u + (size_t)s1 * 128))[q];
                    float e00 = __expf(lrelu(as0.x + adp.x));
                    float e01 = __expf(lrelu(as0.y + adp.y));
                    float e10 = has1 ? __expf(lrelu(as1.x + adp.x)) : 0.f;
                    float e11 = has1 ? __expf(lrelu(as1.y + adp.y)) : 0.f;
                    den0 += e00 + e10;
                    den1 += e01 + e11;
                    float w0 = (q < 16) ? e00 : e01;
                    float w1 = (q < 16) ? e10 : e11;
                    facc2[0] += bfpair(u0.x) * w0 + bfpair(u1.x) * w1;
                    facc2[1] += bfpair(u0.y) * w0 + bfpair(u1.y) * w1;
                    facc2[2] += bfpair(u0.z) * w0 + bfpair(u1.z) * w1;
                    facc2[3] += bfpair(u0.w) * w0 + bfpair(u1.w) * w1;
                }
                float inv = 0.5f / (((q < 16) ? den0 : den1) + 1e-16f);
                #pragma unroll
                for (int m = 0; m < 4; ++m) {
                    facc2[m] *= inv;
                    facc2[m].x += __shfl_xor(facc2[m].x, 16, 64);
                    facc2[m].y += __shfl_xor(facc2[m].y, 16, 64);
                }
                if (q < 16) {
                    int c0 = 8 * q;
                    uint4 o;
                    o.x = packbf(facc2[0].x + p.bias2[c0 + 0], facc2[0].y + p.bias2[c0 + 1]);
                    o.y = packbf(facc2[1].x + p.bias2[c0 + 2], facc2[1].y + p.bias2[c0 + 3]);
                    o.z = packbf(facc2[2].x + p.bias2[c0 + 4], facc2[2].y + p.bias2[c0 + 5]);
                    o.w = packbf(facc2[3].x + p.bias2[c0 + 6], facc2[3].y + p.bias2[c0 + 7]);
                    ((uint4*)((unsigned*)p.h2bf + (size_t)d * 64))[q] = o;
                }
            }
        }
    }
    grid.sync();

    // ================= P9: zsd GEMM =================
    {
        int T = (N + 63) / 64;
        const short8* bf = (const short8*)p.fc2frag;
        for (int tb = blockIdx.x; tb < T; tb += G) {
            int rowbase = (tb * 4 + wv) * 16;
            if (rowbase < N) {
                int arow = rowbase + lo; if (arow >= N) arow = N - 1;
                const __hip_bfloat16* ap = p.h2bf + (size_t)arow * 128 + quad * 8;
                floatx4 acc[16];
                #pragma unroll
                for (int nt = 0; nt < 16; ++nt) acc[nt] = (floatx4){0.f, 0.f, 0.f, 0.f};
                #pragma unroll
                for (int kt = 0; kt < 4; ++kt) {
                    short8 a = *(const short8*)(ap + kt * 32);
                    #pragma unroll
                    for (int nt = 0; nt < 16; ++nt)
                        acc[nt] = __builtin_amdgcn_mfma_f32_16x16x32_bf16(a, bf[(kt * 16 + nt) * 64 + lane], acc[nt], 0, 0, 0);
                }
                #pragma unroll
                for (int nt = 0; nt < 16; ++nt) {
                    int ch = nt * 16 + lo;
                    float bv = (nt >= 8) ? p.fc2_b[ch - 128] : 0.f;
                    #pragma unroll
                    for (int r = 0; r < 4; ++r) {
                        int row = rowbase + quad * 4 + r;
                        if (row < N) ((unsigned short*)p.zsd)[(size_t)row * 256 + ch] = bfbits(acc[nt][r] + bv);
                    }
                }
            }
        }
    }
    grid.sync();

    // ================= P10: edge head =================
    {
        int T = (E + 63) / 64;
        const unsigned* zsd_u = (const unsigned*)p.zsd;
        int g = lane >> 5, r = (lane >> 4) & 1, q = lane & 15;
        v2f f30 = {p.fc3_w[8 * q + 4 * r + 0], p.fc3_w[8 * q + 4 * r + 1]};
        v2f f31 = {p.fc3_w[8 * q + 4 * r + 2], p.fc3_w[8 * q + 4 * r + 3]};
        float b3 = p.fc3_b[0];
        for (int tb = blockIdx.x; tb < T; tb += G) {
            int base = (tb * 4 + wv) * 16;
            if (base < E) {
                int nodes[8];
                #pragma unroll
                for (int j = 0; j < 8; ++j) {
                    int e = base + 2 * j + g;
                    int ec = e < E ? e : E - 1;
                    nodes[j] = r ? p.dst[ec] : p.src[ec];
                }
                uint4 rows[8];
                #pragma unroll
                for (int j = 0; j < 8; ++j)
                    rows[j] = ((const uint4*)(zsd_u + (size_t)nodes[j] * 128 + (r << 6)))[q];
                #pragma unroll
                for (int j = 0; j < 8; ++j) {
                    uint4 mine = rows[j];
                    unsigned sx = (unsigned)__shfl_xor((int)mine.x, 16, 64);
                    unsigned sy = (unsigned)__shfl_xor((int)mine.y, 16, 64);
                    unsigned sz = (unsigned)__shfl_xor((int)mine.z, 16, 64);
                    unsigned sw = (unsigned)__shfl_xor((int)mine.w, 16, 64);
                    unsigned mA = r ? mine.z : mine.x;
                    unsigned mB = r ? mine.w : mine.y;
                    unsigned oA = r ? sz : sx;
                    unsigned oB = r ? sw : sy;
                    v2f sA = bfpair(mA) + bfpair(oA);
                    v2f sB = bfpair(mB) + bfpair(oB);
                    sA.x = fmaxf(sA.x, 0.f); sA.y = fmaxf(sA.y, 0.f);
                    sB.x = fmaxf(sB.x, 0.f); sB.y = fmaxf(sB.y, 0.f);
                    v2f p2 = sA * f30 + sB * f31;
                    float pp = p2.x + p2.y;
                    #pragma unroll
                    for (int off = 1; off < 32; off <<= 1) pp += __shfl_xor(pp, off, 64);
                    int e = base + 2 * j + g;
                    if ((lane & 31) == 0 && e < E)
                        p.out[e] = 1.f / (1.f + expf(-(pp + b3)));
                }
            }
        }
    }
}

extern "C" void kernel_launch(void* const* d_in, const int* in_sizes, int n_in,
                              void* d_out, int out_size, void* d_ws, size_t ws_size,
                              hipStream_t stream) {
    int N = in_sizes[0] / 128;
    int E = in_sizes[1] / 2;
    const int* ei = (const int*)d_in[1];

    float* w = (float*)d_ws;
    size_t off = 0;
    auto alloc = [&](size_t n) { float* p = w + off; off += (n + 63) & ~(size_t)63; return p; };
    float* c1      = alloc(128);
    float* w1fragf = alloc(16384 / 2);
    float* w2fragf = alloc(32768 / 2);
    float* fc2fragf= alloc(32768 / 2);
    float* a_s1    = alloc((size_t)N * 2);
    float* a_d1    = alloc((size_t)N * 2);
    float* a_s2    = alloc((size_t)N * 2);
    float* a_d2    = alloc((size_t)N * 2);
    float* h1bff   = alloc((size_t)N * 64);
    float* hmidf   = alloc((size_t)N * 64);
    float* h2pref  = alloc((size_t)N * 128);
    float* h2bff   = alloc((size_t)N * 64);
    float* zsdf    = alloc((size_t)N * 128);
    int* counts = (int*)alloc(N);
    int* rowp   = (int*)alloc(N + 1);
    int* woff   = (int*)alloc(N);
    int* srcs   = (int*)alloc(E);
    int* bsum   = (int*)alloc(64);
    int* boff   = (int*)alloc(64);

    MegaParams p;
    p.x = (const float*)d_in[0];
    p.src = ei; p.dst = ei + E;
    p.cls = (const float*)d_in[2]; p.fc0_w = (const float*)d_in[3]; p.fc0_b = (const float*)d_in[4];
    p.W1 = (const float*)d_in[5]; p.att_s1 = (const float*)d_in[6]; p.att_d1 = (const float*)d_in[7];
    p.bias1 = (const float*)d_in[8];
    p.W2 = (const float*)d_in[9]; p.att_s2 = (const float*)d_in[10]; p.att_d2 = (const float*)d_in[11];
    p.bias2 = (const float*)d_in[12];
    p.fc2_w = (const float*)d_in[13]; p.fc2_b = (const float*)d_in[14];
    p.fc3_w = (const float*)d_in[15]; p.fc3_b = (const float*)d_in[16];
    p.out = (float*)d_out;
    p.c1 = c1;
    p.w1frag = (__hip_bfloat16*)w1fragf;
    p.w2frag = (__hip_bfloat16*)w2fragf;
    p.fc2frag = (__hip_bfloat16*)fc2fragf;
    p.a_s1 = a_s1; p.a_d1 = a_d1; p.a_s2 = a_s2; p.a_d2 = a_d2;
    p.h1bf = (__hip_bfloat16*)h1bff;
    p.hmid = (__hip_bfloat16*)hmidf;
    p.h2pre = (__hip_bfloat16*)h2pref;
    p.h2bf = (__hip_bfloat16*)h2bff;
    p.zsd = (__hip_bfloat16*)zsdf;
    p.counts = counts; p.rowp = rowp; p.woff = woff; p.srcs = srcs;
    p.bsum = bsum; p.boff = boff;
    p.N = N; p.E = E; p.nb = (N + 1023) / 1024;

    int blocksPerCU = 0;
    hipOccupancyMaxActiveBlocksPerMultiprocessor(&blocksPerCU, mega_kernel, 256, 0);
    int numCU = 0;
    hipDeviceGetAttribute(&numCU, hipDeviceAttributeMultiprocessorCount, 0);
    if (blocksPerCU < 1) blocksPerCU = 1;
    if (numCU < 1) numCU = 256;
    int grid = blocksPerCU * numCU;
    if (grid > 1024) grid = 1024;

    void* args[] = {&p};
    hipLaunchCooperativeKernel((void*)mega_kernel, dim3(grid), dim3(256), args, 0, stream);
}

// Round 11
// 329.376 us; speedup vs baseline: 3.3419x; 3.3419x over previous
//
#include <hip/hip_runtime.h>
#include <hip/hip_bf16.h>
#include <math.h>

// N=50000, E=500000, SED=128, HID=64, H=2, F_node=128
// Round 11: Round 9 base (336us, best) + counts-memset folded into prep +
// unroll-4 gather pipelines in agg1/agg2. NO cooperative launch (R10 showed
// grid.sync costs ~100us+ on gfx950 across 8 XCDs).

typedef short short8 __attribute__((ext_vector_type(8)));
typedef float floatx4 __attribute__((ext_vector_type(4)));
typedef float v2f __attribute__((ext_vector_type(2)));
typedef unsigned uint2v __attribute__((ext_vector_type(2)));

__device__ __forceinline__ v2f bfpair(unsigned v) {
    uint2v t; t.x = v << 16; t.y = v & 0xFFFF0000u;
    return __builtin_bit_cast(v2f, t);
}
__device__ __forceinline__ unsigned short bfbits(float f) {
    return __builtin_bit_cast(unsigned short, __float2bfloat16(f));
}
__device__ __forceinline__ unsigned packbf(float a, float b) {
    return ((unsigned)bfbits(b) << 16) | (unsigned)bfbits(a);
}
__device__ __forceinline__ float lrelu(float v) { return v > 0.f ? v : 0.2f * v; }

// ---- prep: zero counts; sent/c1; bf16 B-fragment tables for W1, W2, fc2 ----
__global__ void prep_kernel(const float* __restrict__ cls, const float* __restrict__ fc0_w,
                            const float* __restrict__ fc0_b, const float* __restrict__ W1,
                            const float* __restrict__ W2, const float* __restrict__ fc2_w,
                            float* __restrict__ c1,
                            __hip_bfloat16* __restrict__ w1frag,
                            __hip_bfloat16* __restrict__ w2frag,
                            __hip_bfloat16* __restrict__ fc2frag,
                            int* __restrict__ counts, int N) {
    int tid = threadIdx.x;
    int gstride = gridDim.x * blockDim.x;
    int g = blockIdx.x * blockDim.x + tid;
    for (int i = g; i < N; i += gstride) counts[i] = 0;
    if (blockIdx.x == 0) {
        __shared__ float s_sent[128];
        if (tid < 128) {
            float acc = fc0_b[tid];
            const float* row = fc0_w + (size_t)tid * 768;
            for (int k = 0; k < 768; ++k) acc += row[k] * cls[k];
            s_sent[tid] = acc;
        }
        __syncthreads();
        if (tid < 128) {
            float acc = 0.f;
            for (int k = 0; k < 128; ++k) acc += s_sent[k] * W1[(128 + k) * 128 + tid];
            c1[tid] = acc;
        }
    }
    for (int i = g; i < 16384; i += gstride) {
        int j = i & 7, l = (i >> 3) & 63, nt = (i >> 9) & 7, kt = (i >> 12) & 3;
        int k = kt * 32 + (l >> 4) * 8 + j;
        int n = nt * 16 + (l & 15);
        w1frag[i] = __float2bfloat16(W1[k * 128 + n]);
    }
    for (int i = g; i < 32768; i += gstride) {
        int j = i & 7, l = (i >> 3) & 63, nt = (i >> 9) & 15, kt = (i >> 13) & 3;
        int k = kt * 32 + (l >> 4) * 8 + j;
        int n = nt * 16 + (l & 15);
        w2frag[i] = __float2bfloat16(W2[k * 256 + n]);
    }
    for (int i = g; i < 32768; i += gstride) {
        int j = i & 7, l = (i >> 3) & 63, nt = (i >> 9) & 15, kt = (i >> 13) & 3;
        int k = kt * 32 + (l >> 4) * 8 + j;
        int n = nt * 16 + (l & 15);
        float v = (n < 128) ? fc2_w[n * 256 + k] : fc2_w[(n - 128) * 256 + 128 + k];
        fc2frag[i] = __float2bfloat16(v);
    }
}

// ---- CSR scan (hierarchical) ----
__global__ void __launch_bounds__(256) bsum_kernel(const int* __restrict__ counts,
                                                   int* __restrict__ bsum, int N) {
    int base = blockIdx.x * 1024;
    int tid = threadIdx.x;
    int v = 0;
    #pragma unroll
    for (int k = 0; k < 4; ++k) {
        int idx = base + k * 256 + tid;
        if (idx < N) v += counts[idx];
    }
    #pragma unroll
    for (int off = 1; off < 64; off <<= 1) v += __shfl_xor(v, off, 64);
    __shared__ int ws[4];
    if ((tid & 63) == 0) ws[tid >> 6] = v;
    __syncthreads();
    if (tid == 0) bsum[blockIdx.x] = ws[0] + ws[1] + ws[2] + ws[3];
}

__global__ void top_scan_kernel(const int* __restrict__ bsum, int* __restrict__ boff, int nb) {
    int lane = threadIdx.x;
    int v = (lane < nb) ? bsum[lane] : 0;
    int x = v;
    #pragma unroll
    for (int off = 1; off < 64; off <<= 1) {
        int t = __shfl_up(x, off, 64);
        if (lane >= off) x += t;
    }
    if (lane < nb) boff[lane] = x - v;
}

__global__ void __launch_bounds__(1024) local_scan_kernel(const int* __restrict__ counts,
                                                          const int* __restrict__ boff,
                                                          int* __restrict__ row, int* __restrict__ woff,
                                                          int N, int E) {
    int tid = threadIdx.x, lane = tid & 63, wv = tid >> 6;
    int base = blockIdx.x * 1024;
    __shared__ int wsum[16];
    int v = (base + tid < N) ? counts[base + tid] : 0;
    int x = v;
    #pragma unroll
    for (int off = 1; off < 64; off <<= 1) {
        int t = __shfl_up(x, off, 64);
        if (lane >= off) x += t;
    }
    if (lane == 63) wsum[wv] = x;
    __syncthreads();
    if (wv == 0 && lane < 16) {
        int y = wsum[lane];
        #pragma unroll
        for (int off = 1; off < 16; off <<= 1) {
            int t = __shfl_up(y, off, 64);
            if (lane >= off) y += t;
        }
        wsum[lane] = y;
    }
    __syncthreads();
    int excl = boff[blockIdx.x] + (wv ? wsum[wv - 1] : 0) + x - v;
    if (base + tid < N) { row[base + tid] = excl; woff[base + tid] = excl; }
    if (blockIdx.x == 0 && tid == 0) row[N] = E;
}

__global__ void scatter_kernel(const int* __restrict__ src, const int* __restrict__ dst,
                               int* __restrict__ woff, int* __restrict__ srcs, int E) {
    int e = blockIdx.x * blockDim.x + threadIdx.x;
    if (e < E) {
        int pos = atomicAdd(&woff[dst[e]], 1);
        srcs[pos] = src[e];
    }
}

// ---- gemm1 MFMA + fused degree count ----
__global__ void __launch_bounds__(256) gemm1_count_kernel(
        const float* __restrict__ x, const __hip_bfloat16* __restrict__ wfrag,
        const float* __restrict__ c1, const float* __restrict__ att_s, const float* __restrict__ att_d,
        __hip_bfloat16* __restrict__ h1bf, float* __restrict__ a_src, float* __restrict__ a_dst,
        const int* __restrict__ dst, int* __restrict__ counts, int E, int G1, int N) {
    if ((int)blockIdx.x >= G1) {
        int e = ((int)blockIdx.x - G1) * 256 + threadIdx.x;
        if (e < E) atomicAdd(&counts[dst[e]], 1);
        return;
    }
    int lane = threadIdx.x & 63, wv = threadIdx.x >> 6;
    int lo = lane & 15, quad = lane >> 4;
    int rowbase = ((int)blockIdx.x * 4 + wv) * 16;
    if (rowbase >= N) return;
    int arow = rowbase + lo; if (arow >= N) arow = N - 1;
    const float* ap = x + (size_t)arow * 128 + quad * 8;
    floatx4 acc[8];
    #pragma unroll
    for (int nt = 0; nt < 8; ++nt) acc[nt] = (floatx4){0.f, 0.f, 0.f, 0.f};
    const short8* bf = (const short8*)wfrag;
    #pragma unroll
    for (int kt = 0; kt < 4; ++kt) {
        float4 fa = *(const float4*)(ap + kt * 32);
        float4 fb = *(const float4*)(ap + kt * 32 + 4);
        short8 a;
        a[0] = (short)bfbits(fa.x); a[1] = (short)bfbits(fa.y);
        a[2] = (short)bfbits(fa.z); a[3] = (short)bfbits(fa.w);
        a[4] = (short)bfbits(fb.x); a[5] = (short)bfbits(fb.y);
        a[6] = (short)bfbits(fb.z); a[7] = (short)bfbits(fb.w);
        #pragma unroll
        for (int nt = 0; nt < 8; ++nt)
            acc[nt] = __builtin_amdgcn_mfma_f32_16x16x32_bf16(a, bf[(kt * 8 + nt) * 64 + lane], acc[nt], 0, 0, 0);
    }
    float ps0[4] = {0,0,0,0}, ps1[4] = {0,0,0,0}, pd0[4] = {0,0,0,0}, pd1[4] = {0,0,0,0};
    #pragma unroll
    for (int nt = 0; nt < 8; ++nt) {
        int ch = nt * 16 + lo;
        float cv = c1[ch], as_v = att_s[ch], ad_v = att_d[ch];
        #pragma unroll
        for (int r = 0; r < 4; ++r) {
            int row = rowbase + quad * 4 + r;
            float val = acc[nt][r] + cv;
            if (row < N) ((unsigned short*)h1bf)[(size_t)row * 128 + ch] = bfbits(val);
            if (nt < 4) { ps0[r] += val * as_v; pd0[r] += val * ad_v; }
            else        { ps1[r] += val * as_v; pd1[r] += val * ad_v; }
        }
    }
    #pragma unroll
    for (int r = 0; r < 4; ++r) {
        int row = rowbase + quad * 4 + r;
        float v0 = ps0[r], v1 = ps1[r], v2 = pd0[r], v3 = pd1[r];
        #pragma unroll
        for (int off = 1; off < 16; off <<= 1) {
            v0 += __shfl_xor(v0, off, 64); v1 += __shfl_xor(v1, off, 64);
            v2 += __shfl_xor(v2, off, 64); v3 += __shfl_xor(v3, off, 64);
        }
        if (lo == 0 && row < N) {
            a_src[row * 2 + 0] = v0; a_src[row * 2 + 1] = v1;
            a_dst[row * 2 + 0] = v2; a_dst[row * 2 + 1] = v3;
        }
    }
}

// ---- agg1: 16 lanes per dst; unroll-4 gather pipeline; ELU -> hmid bf16 ----
__global__ void __launch_bounds__(256) agg1_csr_kernel(
        const int* __restrict__ row, const int* __restrict__ srcs,
        const float* __restrict__ a_src, const float* __restrict__ a_dst,
        const unsigned* __restrict__ h1u, const float* __restrict__ bias1,
        unsigned* __restrict__ hmid_u, int N) {
    int tid = threadIdx.x;
    int d = blockIdx.x * 16 + (tid >> 4);
    if (d >= N) return;
    int q = tid & 15;
    int beg = row[d], end = row[d + 1];
    float2 adp = ((const float2*)a_dst)[d];
    float den0 = 0.f, den1 = 0.f;
    v2f facc2[4];
    #pragma unroll
    for (int m = 0; m < 4; ++m) facc2[m] = (v2f){0.f, 0.f};
    for (int i = beg; i < end; i += 4) {
        bool h1 = (i + 1) < end, h2 = (i + 2) < end, h3 = (i + 3) < end;
        int s0 = srcs[i];
        int s1 = h1 ? srcs[i + 1] : s0;
        int s2 = h2 ? srcs[i + 2] : s0;
        int s3 = h3 ? srcs[i + 3] : s0;
        float2 as0 = ((const float2*)a_src)[s0];
        float2 as1 = ((const float2*)a_src)[s1];
        float2 as2 = ((const float2*)a_src)[s2];
        float2 as3 = ((const float2*)a_src)[s3];
        uint4 u0 = ((const uint4*)(h1u + (size_t)s0 * 64))[q];
        uint4 u1 = ((const uint4*)(h1u + (size_t)s1 * 64))[q];
        uint4 u2 = ((const uint4*)(h1u + (size_t)s2 * 64))[q];
        uint4 u3 = ((const uint4*)(h1u + (size_t)s3 * 64))[q];
        float e00 = __expf(lrelu(as0.x + adp.x));
        float e01 = __expf(lrelu(as0.y + adp.y));
        float e10 = h1 ? __expf(lrelu(as1.x + adp.x)) : 0.f;
        float e11 = h1 ? __expf(lrelu(as1.y + adp.y)) : 0.f;
        float e20 = h2 ? __expf(lrelu(as2.x + adp.x)) : 0.f;
        float e21 = h2 ? __expf(lrelu(as2.y + adp.y)) : 0.f;
        float e30 = h3 ? __expf(lrelu(as3.x + adp.x)) : 0.f;
        float e31 = h3 ? __expf(lrelu(as3.y + adp.y)) : 0.f;
        den0 += e00 + e10 + e20 + e30;
        den1 += e01 + e11 + e21 + e31;
        float w0 = (q < 8) ? e00 : e01;
        float w1 = (q < 8) ? e10 : e11;
        float w2 = (q < 8) ? e20 : e21;
        float w3 = (q < 8) ? e30 : e31;
        facc2[0] += bfpair(u0.x) * w0 + bfpair(u1.x) * w1 + bfpair(u2.x) * w2 + bfpair(u3.x) * w3;
        facc2[1] += bfpair(u0.y) * w0 + bfpair(u1.y) * w1 + bfpair(u2.y) * w2 + bfpair(u3.y) * w3;
        facc2[2] += bfpair(u0.z) * w0 + bfpair(u1.z) * w1 + bfpair(u2.z) * w2 + bfpair(u3.z) * w3;
        facc2[3] += bfpair(u0.w) * w0 + bfpair(u1.w) * w1 + bfpair(u2.w) * w2 + bfpair(u3.w) * w3;
    }
    float inv = 1.f / (((q < 8) ? den0 : den1) + 1e-16f);
    int c0 = 8 * q;
    float v[8];
    #pragma unroll
    for (int m = 0; m < 4; ++m) {
        float va = facc2[m].x * inv + bias1[c0 + 2 * m];
        float vb = facc2[m].y * inv + bias1[c0 + 2 * m + 1];
        v[2 * m]     = va > 0.f ? va : expm1f(va);
        v[2 * m + 1] = vb > 0.f ? vb : expm1f(vb);
    }
    uint4 o;
    o.x = packbf(v[0], v[1]); o.y = packbf(v[2], v[3]);
    o.z = packbf(v[4], v[5]); o.w = packbf(v[6], v[7]);
    ((uint4*)(hmid_u + (size_t)d * 64))[q] = o;
}

// ---- gemm2 MFMA: h2pre[N,256](bf16) = hmid @ W2frag ; logits ----
__global__ void __launch_bounds__(256) gemm2_mfma_kernel(
        const __hip_bfloat16* __restrict__ hmid, const __hip_bfloat16* __restrict__ wfrag,
        const float* __restrict__ att_s, const float* __restrict__ att_d,
        __hip_bfloat16* __restrict__ h2pre, float* __restrict__ a_src, float* __restrict__ a_dst, int N) {
    int lane = threadIdx.x & 63, wv = threadIdx.x >> 6;
    int lo = lane & 15, quad = lane >> 4;
    int rowbase = (blockIdx.x * 4 + wv) * 16;
    if (rowbase >= N) return;
    int arow = rowbase + lo; if (arow >= N) arow = N - 1;
    const __hip_bfloat16* ap = hmid + (size_t)arow * 128 + quad * 8;
    floatx4 acc[16];
    #pragma unroll
    for (int nt = 0; nt < 16; ++nt) acc[nt] = (floatx4){0.f, 0.f, 0.f, 0.f};
    const short8* bf = (const short8*)wfrag;
    #pragma unroll
    for (int kt = 0; kt < 4; ++kt) {
        short8 a = *(const short8*)(ap + kt * 32);
        #pragma unroll
        for (int nt = 0; nt < 16; ++nt)
            acc[nt] = __builtin_amdgcn_mfma_f32_16x16x32_bf16(a, bf[(kt * 16 + nt) * 64 + lane], acc[nt], 0, 0, 0);
    }
    float ps0[4] = {0,0,0,0}, ps1[4] = {0,0,0,0}, pd0[4] = {0,0,0,0}, pd1[4] = {0,0,0,0};
    #pragma unroll
    for (int nt = 0; nt < 16; ++nt) {
        int ch = nt * 16 + lo;
        float as_v = att_s[ch], ad_v = att_d[ch];
        #pragma unroll
        for (int r = 0; r < 4; ++r) {
            int row = rowbase + quad * 4 + r;
            float val = acc[nt][r];
            if (row < N) ((unsigned short*)h2pre)[(size_t)row * 256 + ch] = bfbits(val);
            if (nt < 8) { ps0[r] += val * as_v; pd0[r] += val * ad_v; }
            else        { ps1[r] += val * as_v; pd1[r] += val * ad_v; }
        }
    }
    #pragma unroll
    for (int r = 0; r < 4; ++r) {
        int row = rowbase + quad * 4 + r;
        float v0 = ps0[r], v1 = ps1[r], v2 = pd0[r], v3 = pd1[r];
        #pragma unroll
        for (int off = 1; off < 16; off <<= 1) {
            v0 += __shfl_xor(v0, off, 64); v1 += __shfl_xor(v1, off, 64);
            v2 += __shfl_xor(v2, off, 64); v3 += __shfl_xor(v3, off, 64);
        }
        if (lo == 0 && row < N) {
            a_src[row * 2 + 0] = v0; a_src[row * 2 + 1] = v1;
            a_dst[row * 2 + 0] = v2; a_dst[row * 2 + 1] = v3;
        }
    }
}

// ---- agg2: 32 lanes per dst; unroll-4 pipeline; head-mean via shfl_xor(16) ----
__global__ void __launch_bounds__(256) agg2_csr_kernel(
        const int* __restrict__ row, const int* __restrict__ srcs,
        const float* __restrict__ a_src, const float* __restrict__ a_dst,
        const unsigned* __restrict__ h2u, const float* __restrict__ bias2,
        unsigned* __restrict__ h2bf_u, int N) {
    int tid = threadIdx.x;
    int d = blockIdx.x * 8 + (tid >> 5);
    if (d >= N) return;
    int q = tid & 31;
    int beg = row[d], end = row[d + 1];
    float2 adp = ((const float2*)a_dst)[d];
    float den0 = 0.f, den1 = 0.f;
    v2f facc2[4];
    #pragma unroll
    for (int m = 0; m < 4; ++m) facc2[m] = (v2f){0.f, 0.f};
    for (int i = beg; i < end; i += 4) {
        bool h1 = (i + 1) < end, h2 = (i + 2) < end, h3 = (i + 3) < end;
        int s0 = srcs[i];
        int s1 = h1 ? srcs[i + 1] : s0;
        int s2 = h2 ? srcs[i + 2] : s0;
        int s3 = h3 ? srcs[i + 3] : s0;
        float2 as0 = ((const float2*)a_src)[s0];
        float2 as1 = ((const float2*)a_src)[s1];
        float2 as2 = ((const float2*)a_src)[s2];
        float2 as3 = ((const float2*)a_src)[s3];
        uint4 u0 = ((const uint4*)(h2u + (size_t)s0 * 128))[q];
        uint4 u1 = ((const uint4*)(h2u + (size_t)s1 * 128))[q];
        uint4 u2 = ((const uint4*)(h2u + (size_t)s2 * 128))[q];
        uint4 u3 = ((const uint4*)(h2u + (size_t)s3 * 128))[q];
        float e00 = __expf(lrelu(as0.x + adp.x));
        float e01 = __expf(lrelu(as0.y + adp.y));
        float e10 = h1 ? __expf(lrelu(as1.x + adp.x)) : 0.f;
        float e11 = h1 ? __expf(lrelu(as1.y + adp.y)) : 0.f;
        float e20 = h2 ? __expf(lrelu(as2.x + adp.x)) : 0.f;
        float e21 = h2 ? __expf(lrelu(as2.y + adp.y)) : 0.f;
        float e30 = h3 ? __expf(lrelu(as3.x + adp.x)) : 0.f;
        float e31 = h3 ? __expf(lrelu(as3.y + adp.y)) : 0.f;
        den0 += e00 + e10 + e20 + e30;
        den1 += e01 + e11 + e21 + e31;
        float w0 = (q < 16) ? e00 : e01;
        float w1 = (q < 16) ? e10 : e11;
        float w2 = (q < 16) ? e20 : e21;
        float w3 = (q < 16) ? e30 : e31;
        facc2[0] += bfpair(u0.x) * w0 + bfpair(u1.x) * w1 + bfpair(u2.x) * w2 + bfpair(u3.x) * w3;
        facc2[1] += bfpair(u0.y) * w0 + bfpair(u1.y) * w1 + bfpair(u2.y) * w2 + bfpair(u3.y) * w3;
        facc2[2] += bfpair(u0.z) * w0 + bfpair(u1.z) * w1 + bfpair(u2.z) * w2 + bfpair(u3.z) * w3;
        facc2[3] += bfpair(u0.w) * w0 + bfpair(u1.w) * w1 + bfpair(u2.w) * w2 + bfpair(u3.w) * w3;
    }
    float inv = 0.5f / (((q < 16) ? den0 : den1) + 1e-16f);
    #pragma unroll
    for (int m = 0; m < 4; ++m) {
        facc2[m] *= inv;
        facc2[m].x += __shfl_xor(facc2[m].x, 16, 64);  // combine heads
        facc2[m].y += __shfl_xor(facc2[m].y, 16, 64);
    }
    if (q < 16) {
        int c0 = 8 * q;
        uint4 o;
        o.x = packbf(facc2[0].x + bias2[c0 + 0], facc2[0].y + bias2[c0 + 1]);
        o.y = packbf(facc2[1].x + bias2[c0 + 2], facc2[1].y + bias2[c0 + 3]);
        o.z = packbf(facc2[2].x + bias2[c0 + 4], facc2[2].y + bias2[c0 + 5]);
        o.w = packbf(facc2[3].x + bias2[c0 + 6], facc2[3].y + bias2[c0 + 7]);
        ((uint4*)(h2bf_u + (size_t)d * 64))[q] = o;
    }
}

// ---- zsd MFMA: zsd[N,256](bf16): [zs | zd + fc2_b] = h2bf @ fc2frag ----
__global__ void __launch_bounds__(256) zsd_mfma_kernel(
        const __hip_bfloat16* __restrict__ h2bf, const __hip_bfloat16* __restrict__ wfrag,
        const float* __restrict__ fc2_b, __hip_bfloat16* __restrict__ zsd, int N) {
    int lane = threadIdx.x & 63, wv = threadIdx.x >> 6;
    int lo = lane & 15, quad = lane >> 4;
    int rowbase = (blockIdx.x * 4 + wv) * 16;
    if (rowbase >= N) return;
    int arow = rowbase + lo; if (arow >= N) arow = N - 1;
    const __hip_bfloat16* ap = h2bf + (size_t)arow * 128 + quad * 8;
    floatx4 acc[16];
    #pragma unroll
    for (int nt = 0; nt < 16; ++nt) acc[nt] = (floatx4){0.f, 0.f, 0.f, 0.f};
    const short8* bf = (const short8*)wfrag;
    #pragma unroll
    for (int kt = 0; kt < 4; ++kt) {
        short8 a = *(const short8*)(ap + kt * 32);
        #pragma unroll
        for (int nt = 0; nt < 16; ++nt)
            acc[nt] = __builtin_amdgcn_mfma_f32_16x16x32_bf16(a, bf[(kt * 16 + nt) * 64 + lane], acc[nt], 0, 0, 0);
    }
    #pragma unroll
    for (int nt = 0; nt < 16; ++nt) {
        int ch = nt * 16 + lo;
        float bv = (nt >= 8) ? fc2_b[ch - 128] : 0.f;
        #pragma unroll
        for (int r = 0; r < 4; ++r) {
            int row = rowbase + quad * 4 + r;
            if (row < N) ((unsigned short*)zsd)[(size_t)row * 256 + ch] = bfbits(acc[nt][r] + bv);
        }
    }
}

// ---- edge head: batched gathers (8 rounds), channel-split, shfl_xor(16) add ----
__global__ void __launch_bounds__(256) edge_zsd_kernel(
        const int* __restrict__ src, const int* __restrict__ dst,
        const unsigned* __restrict__ zsd_u, const float* __restrict__ fc3_w,
        const float* __restrict__ fc3_b, float* __restrict__ out, int E) {
    int lane = threadIdx.x & 63, wv = threadIdx.x >> 6;
    int g = lane >> 5, r = (lane >> 4) & 1, q = lane & 15;
    int base = (blockIdx.x * 4 + wv) * 16;
    if (base >= E) return;
    v2f f30 = {fc3_w[8 * q + 4 * r + 0], fc3_w[8 * q + 4 * r + 1]};
    v2f f31 = {fc3_w[8 * q + 4 * r + 2], fc3_w[8 * q + 4 * r + 3]};
    float b3 = fc3_b[0];
    int nodes[8];
    #pragma unroll
    for (int j = 0; j < 8; ++j) {
        int e = base + 2 * j + g;
        int ec = e < E ? e : E - 1;
        nodes[j] = r ? dst[ec] : src[ec];
    }
    uint4 rows[8];
    #pragma unroll
    for (int j = 0; j < 8; ++j)
        rows[j] = ((const uint4*)(zsd_u + (size_t)nodes[j] * 128 + (r << 6)))[q];
    #pragma unroll
    for (int j = 0; j < 8; ++j) {
        uint4 mine = rows[j];
        unsigned sx = (unsigned)__shfl_xor((int)mine.x, 16, 64);
        unsigned sy = (unsigned)__shfl_xor((int)mine.y, 16, 64);
        unsigned sz = (unsigned)__shfl_xor((int)mine.z, 16, 64);
        unsigned sw = (unsigned)__shfl_xor((int)mine.w, 16, 64);
        unsigned mA = r ? mine.z : mine.x;
        unsigned mB = r ? mine.w : mine.y;
        unsigned oA = r ? sz : sx;
        unsigned oB = r ? sw : sy;
        v2f sA = bfpair(mA) + bfpair(oA);
        v2f sB = bfpair(mB) + bfpair(oB);
        sA.x = fmaxf(sA.x, 0.f); sA.y = fmaxf(sA.y, 0.f);
        sB.x = fmaxf(sB.x, 0.f); sB.y = fmaxf(sB.y, 0.f);
        v2f p2 = sA * f30 + sB * f31;
        float p = p2.x + p2.y;
        #pragma unroll
        for (int off = 1; off < 32; off <<= 1) p += __shfl_xor(p, off, 64);
        int e = base + 2 * j + g;
        if ((lane & 31) == 0 && e < E)
            out[e] = 1.f / (1.f + expf(-(p + b3)));
    }
}

extern "C" void kernel_launch(void* const* d_in, const int* in_sizes, int n_in,
                              void* d_out, int out_size, void* d_ws, size_t ws_size,
                              hipStream_t stream) {
    const float* x      = (const float*)d_in[0];
    const int*   ei     = (const int*)d_in[1];
    const float* cls    = (const float*)d_in[2];
    const float* fc0_w  = (const float*)d_in[3];
    const float* fc0_b  = (const float*)d_in[4];
    const float* W1     = (const float*)d_in[5];
    const float* att_s1 = (const float*)d_in[6];
    const float* att_d1 = (const float*)d_in[7];
    const float* bias1  = (const float*)d_in[8];
    const float* W2     = (const float*)d_in[9];
    const float* att_s2 = (const float*)d_in[10];
    const float* att_d2 = (const float*)d_in[11];
    const float* bias2  = (const float*)d_in[12];
    const float* fc2_w  = (const float*)d_in[13];
    const float* fc2_b  = (const float*)d_in[14];
    const float* fc3_w  = (const float*)d_in[15];
    const float* fc3_b  = (const float*)d_in[16];
    float* out = (float*)d_out;

    int N = in_sizes[0] / 128;
    int E = in_sizes[1] / 2;
    const int* src = ei;
    const int* dst = ei + E;
    int nb = (N + 1023) / 1024;

    float* w = (float*)d_ws;
    size_t off = 0;
    auto alloc = [&](size_t n) { float* p = w + off; off += (n + 63) & ~(size_t)63; return p; };
    float* c1      = alloc(128);
    float* w1fragf = alloc(16384 / 2);
    float* w2fragf = alloc(32768 / 2);
    float* fc2fragf= alloc(32768 / 2);
    float* a_s1    = alloc((size_t)N * 2);
    float* a_d1    = alloc((size_t)N * 2);
    float* a_s2    = alloc((size_t)N * 2);
    float* a_d2    = alloc((size_t)N * 2);
    float* h1bff   = alloc((size_t)N * 64);   // N*128 bf16
    float* hmidf   = alloc((size_t)N * 64);   // N*128 bf16
    float* h2pref  = alloc((size_t)N * 128);  // N*256 bf16
    float* h2bff   = alloc((size_t)N * 64);   // N*128 bf16
    float* zsdf    = alloc((size_t)N * 128);  // N*256 bf16
    int* counts = (int*)alloc(N);
    int* rowp   = (int*)alloc(N + 1);
    int* woff   = (int*)alloc(N);
    int* srcs   = (int*)alloc(E);
    int* bsum   = (int*)alloc(64);
    int* boff   = (int*)alloc(64);
    __hip_bfloat16* w1frag = (__hip_bfloat16*)w1fragf;
    __hip_bfloat16* w2frag = (__hip_bfloat16*)w2fragf;
    __hip_bfloat16* fc2frag= (__hip_bfloat16*)fc2fragf;
    __hip_bfloat16* hmid   = (__hip_bfloat16*)hmidf;
    __hip_bfloat16* h2pre  = (__hip_bfloat16*)h2pref;
    __hip_bfloat16* h2bf   = (__hip_bfloat16*)h2bff;
    __hip_bfloat16* h1bf   = (__hip_bfloat16*)h1bff;
    __hip_bfloat16* zsd    = (__hip_bfloat16*)zsdf;

    prep_kernel<<<64, 256, 0, stream>>>(cls, fc0_w, fc0_b, W1, W2, fc2_w, c1, w1frag, w2frag, fc2frag,
                                        counts, N);
    int G1 = (N + 63) / 64;
    int G2 = (E + 255) / 256;
    gemm1_count_kernel<<<G1 + G2, 256, 0, stream>>>(x, w1frag, c1, att_s1, att_d1, h1bf, a_s1, a_d1,
                                                    dst, counts, E, G1, N);
    bsum_kernel<<<nb, 256, 0, stream>>>(counts, bsum, N);
    top_scan_kernel<<<1, 64, 0, stream>>>(bsum, boff, nb);
    local_scan_kernel<<<nb, 1024, 0, stream>>>(counts, boff, rowp, woff, N, E);
    scatter_kernel<<<(E + 255) / 256, 256, 0, stream>>>(src, dst, woff, srcs, E);
    agg1_csr_kernel<<<(N + 15) / 16, 256, 0, stream>>>(rowp, srcs, a_s1, a_d1, (const unsigned*)h1bf, bias1, (unsigned*)hmid, N);
    gemm2_mfma_kernel<<<(N + 63) / 64, 256, 0, stream>>>(hmid, w2frag, att_s2, att_d2, h2pre, a_s2, a_d2, N);
    agg2_csr_kernel<<<(N + 7) / 8, 256, 0, stream>>>(rowp, srcs, a_s2, a_d2, (const unsigned*)h2pre, bias2, (unsigned*)h2bf, N);
    zsd_mfma_kernel<<<(N + 63) / 64, 256, 0, stream>>>(h2bf, fc2frag, fc2_b, zsd, N);
    edge_zsd_kernel<<<(E + 63) / 64, 256, 0, stream>>>(src, dst, (const unsigned*)zsd, fc3_w, fc3_b, out, E);
}